// Round 8
// baseline (879.709 us; speedup 1.0000x reference)
//
#include <hip/hip_runtime.h>
#include <hip/hip_bf16.h>

#define B 64
#define S 4096
#define H 256
#define BM 128
#define BK 32

typedef short bf16x8 __attribute__((ext_vector_type(8)));
typedef float f32x4 __attribute__((ext_vector_type(4)));

// ---------------------------------------------------------------------------
// Split Wk (f32 [H][H], K-major rows) into hi/lo bf16 planes.
__global__ __launch_bounds__(256) void wk_split(const float* __restrict__ Wk,
                                                unsigned short* __restrict__ WkHi,
                                                unsigned short* __restrict__ WkLo) {
    int i = (blockIdx.x * 256 + threadIdx.x) * 4;
    float4 x = *(const float4*)(Wk + i);
    float f[4] = {x.x, x.y, x.z, x.w};
    unsigned int hw[2], lw[2];
    #pragma unroll
    for (int j = 0; j < 2; ++j) {
        unsigned int u0 = __float_as_uint(f[2 * j]);
        unsigned int u1 = __float_as_uint(f[2 * j + 1]);
        float h0 = __uint_as_float(u0 & 0xFFFF0000u);
        float h1 = __uint_as_float(u1 & 0xFFFF0000u);
        unsigned int l0 = __float_as_uint(f[2 * j] - h0) >> 16;
        unsigned int l1 = __float_as_uint(f[2 * j + 1] - h1) >> 16;
        hw[j] = (u0 >> 16) | (u1 & 0xFFFF0000u);
        lw[j] = l0 | (l1 << 16);
    }
    *(uint2*)(WkHi + i) = make_uint2(hw[0], hw[1]);
    *(uint2*)(WkLo + i) = make_uint2(lw[0], lw[1]);
}

// ---------------------------------------------------------------------------
// q_proj[b][h] = sum_g query[b][g] * Wq[h][g]
__global__ __launch_bounds__(256) void qproj_kernel(const float* __restrict__ query,
                                                    const float* __restrict__ Wq,
                                                    float* __restrict__ qp) {
    int b = blockIdx.x, h = threadIdx.x;
    __shared__ float qrow[H];
    qrow[h] = query[b * H + h];
    __syncthreads();
    const float* wrow = Wq + h * H;
    float acc = 0.f;
    #pragma unroll 8
    for (int g = 0; g < H; g += 4) {
        float4 w = *(const float4*)(wrow + g);
        acc += w.x * qrow[g] + w.y * qrow[g + 1] + w.z * qrow[g + 2] + w.w * qrow[g + 3];
    }
    qp[b * H + h] = acc;
}

// ---------------------------------------------------------------------------
// scores[b][s] = sum_h V[h] * tanh(qp[b][h] + sum_g keys[b][s][g]*Wk[h][g])
// Split-bf16 3-pass MFMA GEMM, 128x256 tile, K=256 in 8 chunks of 32.
// Raw-barrier pipeline: lgkmcnt(0)-only before s_barrier so global prefetch
// loads stay in flight across barriers (counted vmcnt at use). A prefetch is
// 2-deep (HBM ~900cyc), B 1-deep (L2-resident planes). Loop fully unrolled so
// all prefetch-bank indices are static (no scratch).
__global__ __launch_bounds__(512, 4) void scores_kernel(
    const float* __restrict__ keys,
    const unsigned short* __restrict__ WkHi,
    const unsigned short* __restrict__ WkLo,
    const float* __restrict__ qp,
    const float* __restrict__ V,
    float* __restrict__ scores)
{
    __shared__ unsigned short Ahi[BM][40], Alo[BM][40];
    __shared__ unsigned short Bhi[H][40], Blo[H][40];
    __shared__ float part[4][BM];

    const int b  = blockIdx.y;
    const int s0 = blockIdx.x * BM;
    const int tid  = threadIdx.x;
    const int lane = tid & 63;
    const int wid  = tid >> 6;
    const int lr = lane & 15, lg = lane >> 4;
    const int mg = wid >> 2, ng = wid & 3;  // wave tile origin: (mg*64, ng*64)

    const int ar = tid >> 2;             // A row 0..127 (4 threads/row)
    const int ak = (tid & 3) * 8;        // A k-offset {0,8,16,24}
    const int br = tid >> 1;             // B row 0..255 (2 threads/row)
    const int bk = (tid & 1) * 16;       // B k-offset {0,16}

    const float* aptr = keys + ((size_t)(b * S + s0 + ar)) * H + ak;
    const unsigned short* bhptr = WkHi + br * H + bk;
    const unsigned short* blptr = WkLo + br * H + bk;

    f32x4 acc[4][4];
    #pragma unroll
    for (int mi = 0; mi < 4; ++mi)
        #pragma unroll
        for (int ni = 0; ni < 4; ++ni) acc[mi][ni] = (f32x4){0.f, 0.f, 0.f, 0.f};

    float qv[4], vv[4];
    #pragma unroll
    for (int ni = 0; ni < 4; ++ni) {
        int c = ng * 64 + ni * 16 + lr;
        qv[ni] = qp[b * H + c];
        vv[ni] = V[c];
    }

    // prologue: B[0] 1-deep; A[0],A[1] 2-deep (issue order: B0, A0, A1 so
    // counted vmcnt waits release in consumption order)
    uint4 bp0, bp1, bp2, bp3;
    float4 a0A, a1A, a0B, a1B;  // bank A = even chunks, bank B = odd chunks
    bp0 = *(const uint4*)(bhptr);
    bp1 = *(const uint4*)(bhptr + 8);
    bp2 = *(const uint4*)(blptr);
    bp3 = *(const uint4*)(blptr + 8);
    a0A = *(const float4*)(aptr);
    a1A = *(const float4*)(aptr + 4);
    a0B = *(const float4*)(aptr + BK);
    a1B = *(const float4*)(aptr + BK + 4);

    #pragma unroll
    for (int t = 0; t < 8; ++t) {
        // --- stage chunk t: regs -> LDS (A converts f32 -> hi/lo bf16) ---
        float4 a0 = (t & 1) ? a0B : a0A;
        float4 a1 = (t & 1) ? a1B : a1A;
        {
            float f[8] = {a0.x, a0.y, a0.z, a0.w, a1.x, a1.y, a1.z, a1.w};
            unsigned int hw[4], lw[4];
            #pragma unroll
            for (int j = 0; j < 4; ++j) {
                unsigned int u0 = __float_as_uint(f[2 * j]);
                unsigned int u1 = __float_as_uint(f[2 * j + 1]);
                float h0 = __uint_as_float(u0 & 0xFFFF0000u);
                float h1 = __uint_as_float(u1 & 0xFFFF0000u);
                unsigned int l0 = __float_as_uint(f[2 * j] - h0) >> 16;
                unsigned int l1 = __float_as_uint(f[2 * j + 1] - h1) >> 16;
                hw[j] = (u0 >> 16) | (u1 & 0xFFFF0000u);
                lw[j] = l0 | (l1 << 16);
            }
            *(uint4*)&Ahi[ar][ak] = make_uint4(hw[0], hw[1], hw[2], hw[3]);
            *(uint4*)&Alo[ar][ak] = make_uint4(lw[0], lw[1], lw[2], lw[3]);
        }
        *(uint4*)&Bhi[br][bk] = bp0;
        *(uint4*)&Bhi[br][bk + 8] = bp1;
        *(uint4*)&Blo[br][bk] = bp2;
        *(uint4*)&Blo[br][bk + 8] = bp3;

        // --- issue prefetches (stay in flight across the raw barrier) ---
        if (t < 7) {
            int k1 = (t + 1) * BK;
            bp0 = *(const uint4*)(bhptr + k1);
            bp1 = *(const uint4*)(bhptr + k1 + 8);
            bp2 = *(const uint4*)(blptr + k1);
            bp3 = *(const uint4*)(blptr + k1 + 8);
        }
        if (t < 6) {
            int k2 = (t + 2) * BK;
            if (t & 1) {
                a0B = *(const float4*)(aptr + k2);
                a1B = *(const float4*)(aptr + k2 + 4);
            } else {
                a0A = *(const float4*)(aptr + k2);
                a1A = *(const float4*)(aptr + k2 + 4);
            }
        }

        __builtin_amdgcn_sched_barrier(0);
        asm volatile("s_waitcnt lgkmcnt(0)" ::: "memory");  // LDS writes visible
        __builtin_amdgcn_s_barrier();                        // NO vmcnt drain
        __builtin_amdgcn_sched_barrier(0);

        // --- compute chunk t ---
        bf16x8 bhf[4], blf[4];
        #pragma unroll
        for (int ni = 0; ni < 4; ++ni) {
            bhf[ni] = *(const bf16x8*)&Bhi[ng * 64 + ni * 16 + lr][lg * 8];
            blf[ni] = *(const bf16x8*)&Blo[ng * 64 + ni * 16 + lr][lg * 8];
        }
        #pragma unroll
        for (int mi = 0; mi < 4; ++mi) {
            bf16x8 ah = *(const bf16x8*)&Ahi[mg * 64 + mi * 16 + lr][lg * 8];
            bf16x8 al = *(const bf16x8*)&Alo[mg * 64 + mi * 16 + lr][lg * 8];
            #pragma unroll
            for (int ni = 0; ni < 4; ++ni) {
                acc[mi][ni] = __builtin_amdgcn_mfma_f32_16x16x32_bf16(ah, bhf[ni], acc[mi][ni], 0, 0, 0);
                acc[mi][ni] = __builtin_amdgcn_mfma_f32_16x16x32_bf16(ah, blf[ni], acc[mi][ni], 0, 0, 0);
                acc[mi][ni] = __builtin_amdgcn_mfma_f32_16x16x32_bf16(al, bhf[ni], acc[mi][ni], 0, 0, 0);
            }
        }

        __builtin_amdgcn_sched_barrier(0);
        __builtin_amdgcn_s_barrier();   // protect LDS reuse next chunk
    }

    // --- epilogue: p[s] = sum_h V[h]*tanh(qp[h] + C[s,h]) ---
    // C/D layout: col = lane&15, row = (lane>>4)*4 + reg  [m89-verified]
    #pragma unroll
    for (int mi = 0; mi < 4; ++mi) {
        #pragma unroll
        for (int r = 0; r < 4; ++r) {
            float p = 0.f;
            #pragma unroll
            for (int ni = 0; ni < 4; ++ni) {
                float x = qv[ni] + acc[mi][ni][r];
                float e = __expf(2.f * x);
                float tnh = 1.f - 2.f / (e + 1.f);
                p += vv[ni] * tnh;
            }
            p += __shfl_xor(p, 1);
            p += __shfl_xor(p, 2);
            p += __shfl_xor(p, 4);
            p += __shfl_xor(p, 8);
            if (lr == 0) part[ng][mg * 64 + mi * 16 + lg * 4 + r] = p;
        }
    }
    __syncthreads();
    if (tid < BM) {
        float sc = part[0][tid] + part[1][tid] + part[2][tid] + part[3][tid];
        scores[(size_t)b * S + s0 + tid] = sc;
    }
}

// ---------------------------------------------------------------------------
// softmax over each row of scores [B][S]. grid(B), block(1024): 4 elems/thread.
__global__ __launch_bounds__(1024) void softmax_kernel(const float* __restrict__ scores,
                                                       float* __restrict__ weights) {
    __shared__ float red[16];
    int b = blockIdx.x, tid = threadIdx.x;
    int lane = tid & 63, wid = tid >> 6;
    const float* src = scores + (size_t)b * S;

    float4 v = *(const float4*)(src + tid * 4);
    float m = fmaxf(fmaxf(v.x, v.y), fmaxf(v.z, v.w));
    #pragma unroll
    for (int off = 32; off; off >>= 1) m = fmaxf(m, __shfl_xor(m, off));
    if (lane == 0) red[wid] = m;
    __syncthreads();
    float M = red[0];
    #pragma unroll
    for (int i = 1; i < 16; ++i) M = fmaxf(M, red[i]);
    __syncthreads();

    v.x = __expf(v.x - M);
    v.y = __expf(v.y - M);
    v.z = __expf(v.z - M);
    v.w = __expf(v.w - M);
    float sum = v.x + v.y + v.z + v.w;
    #pragma unroll
    for (int off = 32; off; off >>= 1) sum += __shfl_xor(sum, off);
    if (lane == 0) red[wid] = sum;
    __syncthreads();
    float tot = 0.f;
    #pragma unroll
    for (int i = 0; i < 16; ++i) tot += red[i];
    float inv = 1.f / tot;

    v.x *= inv; v.y *= inv; v.z *= inv; v.w *= inv;
    *(float4*)(weights + (size_t)b * S + tid * 4) = v;
}

// ---------------------------------------------------------------------------
// context partials: partial[c][b][h] = sum_{s in chunk c} w[s]*keys[b][s][h]
// grid(32 s-chunks, B), block(256); no atomics.
__global__ __launch_bounds__(256) void context_partial(const float* __restrict__ keys,
                                                       const float* __restrict__ weights,
                                                       float* __restrict__ partial) {
    int b = blockIdx.y, chunk = blockIdx.x, tid = threadIdx.x;
    __shared__ float w[128];
    if (tid < 128) w[tid] = weights[(size_t)b * S + chunk * 128 + tid];
    __syncthreads();

    int sl = tid >> 6;
    int h4 = (tid & 63) * 4;
    float4 acc = {0.f, 0.f, 0.f, 0.f};
    const float* kb = keys + ((size_t)(b * S + chunk * 128)) * H;
    #pragma unroll 4
    for (int s = sl; s < 128; s += 4) {
        float ws = w[s];
        float4 k4 = *(const float4*)(kb + (size_t)s * H + h4);
        acc.x += ws * k4.x;
        acc.y += ws * k4.y;
        acc.z += ws * k4.z;
        acc.w += ws * k4.w;
    }

    __shared__ float4 partc[4][64];
    partc[sl][tid & 63] = acc;
    __syncthreads();
    if (sl == 0) {
        float4 t = partc[0][tid];
        #pragma unroll
        for (int g = 1; g < 4; ++g) {
            float4 p = partc[g][tid];
            t.x += p.x; t.y += p.y; t.z += p.z; t.w += p.w;
        }
        *(float4*)&partial[((size_t)chunk * B + b) * H + h4] = t;
    }
}

// ---------------------------------------------------------------------------
// ctx[b][h] = sum_c partial[c][b][h]. grid(B), block(256). Overwrites ctx.
__global__ __launch_bounds__(256) void ctx_reduce(const float* __restrict__ partial,
                                                  float* __restrict__ ctx) {
    int b = blockIdx.x, h = threadIdx.x;
    float s = 0.f;
    #pragma unroll
    for (int c = 0; c < 32; ++c) s += partial[((size_t)c * B + b) * H + h];
    ctx[b * H + h] = s;
}

// ---------------------------------------------------------------------------
extern "C" void kernel_launch(void* const* d_in, const int* in_sizes, int n_in,
                              void* d_out, int out_size, void* d_ws, size_t ws_size,
                              hipStream_t stream) {
    const float* query = (const float*)d_in[0];  // [B,H]
    const float* keys  = (const float*)d_in[1];  // [B,S,H]
    const float* Wq    = (const float*)d_in[2];  // [H,H]
    const float* Wk    = (const float*)d_in[3];  // [H,H]
    const float* V     = (const float*)d_in[4];  // [H]

    float* ctx     = (float*)d_out;            // [B,H]
    float* weights = (float*)d_out + B * H;    // [B,S]

    float* qp            = (float*)d_ws;                       // 16384 f32
    unsigned short* WkHi = (unsigned short*)(qp + B * H);      // 65536 bf16
    unsigned short* WkLo = WkHi + H * H;                       // 65536 bf16
    float* scoresBuf     = (float*)(WkLo + H * H);             // 262144 f32
    float* partial       = scoresBuf + (size_t)B * S;          // 524288 f32

    wk_split<<<64, 256, 0, stream>>>(Wk, WkHi, WkLo);
    qproj_kernel<<<B, 256, 0, stream>>>(query, Wq, qp);
    scores_kernel<<<dim3(S / BM, B), 512, 0, stream>>>(keys, WkHi, WkLo, qp, V, scoresBuf);
    softmax_kernel<<<B, 1024, 0, stream>>>(scoresBuf, weights);
    context_partial<<<dim3(32, B), 256, 0, stream>>>(keys, weights, partial);
    ctx_reduce<<<B, 256, 0, stream>>>(partial, ctx);
}